// Round 2
// baseline (5157.333 us; speedup 1.0000x reference)
//
#include <hip/hip_runtime.h>
#include <math.h>

#define B 8
#define L 513
#define D 512
#define H 8
#define HS 64
#define V 513
#define NL 6
#define BL (B * L)          // 4104
#define EPS 1e-5f

// ---------------------------------------------------------------------------
// embed + positional: h[b,l,:] = embed[x[b,l],:] + pos_embed[l,:]
// ---------------------------------------------------------------------------
__global__ __launch_bounds__(256) void embed_k(const int* __restrict__ x,
                                               const float* __restrict__ emb,
                                               const float* __restrict__ pos,
                                               float* __restrict__ hbuf)
{
    int row = blockIdx.x;            // 0..BL-1
    int l   = row % L;
    int tok = x[row];
    const float* er = emb + (size_t)tok * D;
    const float* pr = pos + (size_t)l * D;
    float* hr = hbuf + (size_t)row * D;
    for (int d = threadIdx.x; d < D; d += 256)
        hr[d] = er[d] + pr[d];
}

// ---------------------------------------------------------------------------
// LayerNorm: one block (256 thr) per row, D=512 -> 2 elems/thread
// ---------------------------------------------------------------------------
__global__ __launch_bounds__(256) void ln_k(const float* __restrict__ x,
                                            const float* __restrict__ g,
                                            const float* __restrict__ b,
                                            float* __restrict__ o)
{
    const int row = blockIdx.x, tid = threadIdx.x;
    const float* xr = x + (size_t)row * D;
    float v0 = xr[tid], v1 = xr[tid + 256];
    __shared__ float red[256];
    red[tid] = v0 + v1;
    __syncthreads();
    for (int off = 128; off > 0; off >>= 1) {
        if (tid < off) red[tid] += red[tid + off];
        __syncthreads();
    }
    float mu = red[0] * (1.f / D);
    __syncthreads();
    float d0 = v0 - mu, d1 = v1 - mu;
    red[tid] = d0 * d0 + d1 * d1;
    __syncthreads();
    for (int off = 128; off > 0; off >>= 1) {
        if (tid < off) red[tid] += red[tid + off];
        __syncthreads();
    }
    float rs = rsqrtf(red[0] * (1.f / D) + EPS);
    float* orow = o + (size_t)row * D;
    orow[tid]       = d0 * rs * g[tid]       + b[tid];
    orow[tid + 256] = d1 * rs * g[tid + 256] + b[tid + 256];
}

// ---------------------------------------------------------------------------
// Tiled fp32 GEMM, 64x64 tile, 256 threads (16x16, 4x4 micro-tile), K=D=512.
// MODE 0: QKV projection. Bm = W[h][d][e] (H,D,HS); out scattered to (B,H,L,HS).
// MODE 1: MLP. Bm row-major (D,D); out = gelu(acc+bias) + outp (in-place h).
// MODE 2: FC.  Bm row-major (D,N);  out = acc + bias (N=513, bounds-checked).
// ---------------------------------------------------------------------------
template <int MODE>
__global__ __launch_bounds__(256) void gemm_k(const float* __restrict__ A,
                                              const float* __restrict__ Bm,
                                              const float* __restrict__ bias,
                                              float* __restrict__ outp,
                                              int M, int N)
{
    __shared__ float As[16][65];   // [kk][r]
    __shared__ float Bs[16][65];   // [kk][c]
    const int tid  = threadIdx.x;
    const int row0 = blockIdx.y * 64;
    const int col0 = blockIdx.x * 64;
    const int tx = tid & 15, ty = tid >> 4;
    float acc[4][4] = {};

    for (int k0 = 0; k0 < D; k0 += 16) {
#pragma unroll
        for (int i = 0; i < 4; ++i) {
            int idx = tid + i * 256;
            int r = idx >> 4, kk = idx & 15;
            float av = 0.f;
            if (row0 + r < M) av = A[(size_t)(row0 + r) * D + k0 + kk];
            As[kk][r] = av;
        }
#pragma unroll
        for (int i = 0; i < 4; ++i) {
            int idx = tid + i * 256;
            int c = idx & 63, kk = idx >> 6;
            float bv;
            if (MODE == 0) {
                // head = blockIdx.x (tile width == HS == 64), e = c
                bv = Bm[(size_t)blockIdx.x * D * HS + (size_t)(k0 + kk) * HS + c];
            } else if (MODE == 1) {
                bv = Bm[(size_t)(k0 + kk) * D + col0 + c];
            } else {
                bv = (col0 + c < N) ? Bm[(size_t)(k0 + kk) * N + col0 + c] : 0.f;
            }
            Bs[kk][c] = bv;
        }
        __syncthreads();
#pragma unroll
        for (int kk = 0; kk < 16; ++kk) {
            float a[4], b[4];
#pragma unroll
            for (int j = 0; j < 4; ++j) { a[j] = As[kk][ty * 4 + j]; b[j] = Bs[kk][tx * 4 + j]; }
#pragma unroll
            for (int i2 = 0; i2 < 4; ++i2)
#pragma unroll
                for (int j = 0; j < 4; ++j) acc[i2][j] += a[i2] * b[j];
        }
        __syncthreads();
    }

#pragma unroll
    for (int i = 0; i < 4; ++i) {
        int r = row0 + ty * 4 + i;
        if (r >= M) continue;
#pragma unroll
        for (int j = 0; j < 4; ++j) {
            int c = col0 + tx * 4 + j;
            float val = acc[i][j];
            if (MODE == 0) {
                int b_ = r / L, l = r % L;
                int head = c >> 6, e = c & 63;
                outp[(((size_t)b_ * H + head) * L + l) * HS + e] = val;
            } else if (MODE == 1) {
                float xv = val + bias[c];
                float gl = 0.5f * xv * (1.f + erff(xv * 0.70710678118654752f));
                outp[(size_t)r * D + c] = gl + outp[(size_t)r * D + c];
            } else {
                if (c < N) outp[(size_t)r * N + c] = val + bias[c];
            }
        }
    }
}

// ---------------------------------------------------------------------------
// Attention: one block (256 thr) per (b, h, query-row). Scores row in LDS.
// Fused residual: h[b,lq,head*HS+e] += y[e].
// ---------------------------------------------------------------------------
__global__ __launch_bounds__(256) void attn_k(const float* __restrict__ q,
                                              const float* __restrict__ k,
                                              const float* __restrict__ v,
                                              float* __restrict__ hbuf)
{
    const int idx = blockIdx.x;
    const int bh = idx / L;          // b*H + h
    const int lq = idx % L;
    const int tid = threadIdx.x;

    __shared__ float qs[HS];
    __shared__ float s[L];
    __shared__ float red[256];
    __shared__ float yacc[4][HS];

    if (tid < HS) qs[tid] = q[((size_t)bh * L + lq) * HS + tid];
    __syncthreads();

    const int nm = lq + 1;
    const float scale = 0.125f;      // HS^-0.5

    for (int m = tid; m < nm; m += 256) {
        const float* kr = k + ((size_t)bh * L + m) * HS;
        float acc = 0.f;
#pragma unroll
        for (int e = 0; e < HS; e += 4) {
            float4 kv = *(const float4*)(kr + e);
            acc += qs[e] * kv.x + qs[e + 1] * kv.y + qs[e + 2] * kv.z + qs[e + 3] * kv.w;
        }
        s[m] = acc * scale;
    }
    __syncthreads();

    // row max
    float mx = -INFINITY;
    for (int m = tid; m < nm; m += 256) mx = fmaxf(mx, s[m]);
    red[tid] = mx;
    __syncthreads();
    for (int off = 128; off > 0; off >>= 1) {
        if (tid < off) red[tid] = fmaxf(red[tid], red[tid + off]);
        __syncthreads();
    }
    mx = red[0];
    __syncthreads();

    // exp + sum
    float sum = 0.f;
    for (int m = tid; m < nm; m += 256) {
        float e_ = expf(s[m] - mx);
        s[m] = e_;
        sum += e_;
    }
    red[tid] = sum;
    __syncthreads();
    for (int off = 128; off > 0; off >>= 1) {
        if (tid < off) red[tid] += red[tid + off];
        __syncthreads();
    }
    const float inv = 1.f / red[0];

    // PV: 4 groups of 64 lanes; lane = e, group-strided over m
    const int e = tid & 63, grp = tid >> 6;
    float a = 0.f;
    for (int m = grp; m < nm; m += 4)
        a += s[m] * v[((size_t)bh * L + m) * HS + e];
    yacc[grp][e] = a;
    __syncthreads();
    if (grp == 0) {
        float y = (yacc[0][e] + yacc[1][e] + yacc[2][e] + yacc[3][e]) * inv;
        int b_ = bh / H, hh = bh % H;
        size_t off2 = ((size_t)b_ * L + lq) * D + hh * HS + e;
        hbuf[off2] = hbuf[off2] + y;
    }
}

// ---------------------------------------------------------------------------
extern "C" void kernel_launch(void* const* d_in, const int* in_sizes, int n_in,
                              void* d_out, int out_size, void* d_ws, size_t ws_size,
                              hipStream_t stream)
{
    const int*   x    = (const int*)d_in[0];
    const float* emb  = (const float*)d_in[1];
    const float* pos  = (const float*)d_in[2];
    const float* Wq   = (const float*)d_in[3];
    const float* Wk   = (const float*)d_in[4];
    const float* Wv   = (const float*)d_in[5];
    const float* ln1g = (const float*)d_in[6];
    const float* ln1b = (const float*)d_in[7];
    const float* ln2g = (const float*)d_in[8];
    const float* ln2b = (const float*)d_in[9];
    const float* mlpW = (const float*)d_in[10];
    const float* mlpb = (const float*)d_in[11];
    const float* fcW  = (const float*)d_in[12];
    const float* fcb  = (const float*)d_in[13];
    float* out = (float*)d_out;

    float* h  = (float*)d_ws;
    float* xn = h  + (size_t)BL * D;
    float* q  = xn + (size_t)BL * D;
    float* k  = q  + (size_t)BL * D;
    float* v  = k  + (size_t)BL * D;

    embed_k<<<BL, 256, 0, stream>>>(x, emb, pos, h);

    dim3 g8(8, 65);   // 512/64 cols, ceil(4104/64) rows
    dim3 g9(9, 65);   // ceil(513/64) cols

    for (int i = 0; i < NL; ++i) {
        ln_k<<<BL, 256, 0, stream>>>(h, ln1g + i * D, ln1b + i * D, xn);
        gemm_k<0><<<g8, 256, 0, stream>>>(xn, Wq + (size_t)i * H * D * HS, nullptr, q, BL, D);
        gemm_k<0><<<g8, 256, 0, stream>>>(xn, Wk + (size_t)i * H * D * HS, nullptr, k, BL, D);
        gemm_k<0><<<g8, 256, 0, stream>>>(xn, Wv + (size_t)i * H * D * HS, nullptr, v, BL, D);
        attn_k<<<B * H * L, 256, 0, stream>>>(q, k, v, h);
        ln_k<<<BL, 256, 0, stream>>>(h, ln2g + i * D, ln2b + i * D, xn);
        gemm_k<1><<<g8, 256, 0, stream>>>(xn, mlpW + (size_t)i * D * D, mlpb + i * D, h, BL, D);
    }
    gemm_k<2><<<g9, 256, 0, stream>>>(h, fcW, fcb, out, BL, V);
}

// Round 4
// 2569.110 us; speedup vs baseline: 2.0074x; 2.0074x over previous
//
#include <hip/hip_runtime.h>
#include <math.h>

#define B 8
#define L 513
#define D 512
#define H 8
#define HS 64
#define V 513
#define NL 6
#define BL (B * L)          // 4104
#define EPS 1e-5f

// ---------------------------------------------------------------------------
// embed + positional: h[b,l,:] = embed[x[b,l],:] + pos_embed[l,:]
// ---------------------------------------------------------------------------
__global__ __launch_bounds__(256) void embed_k(const int* __restrict__ x,
                                               const float* __restrict__ emb,
                                               const float* __restrict__ pos,
                                               float* __restrict__ hbuf)
{
    int row = blockIdx.x;            // 0..BL-1
    int l   = row % L;
    int tok = x[row];
    const float* er = emb + (size_t)tok * D;
    const float* pr = pos + (size_t)l * D;
    float* hr = hbuf + (size_t)row * D;
    for (int d = threadIdx.x; d < D; d += 256)
        hr[d] = er[d] + pr[d];
}

// ---------------------------------------------------------------------------
// LayerNorm: one block (256 thr) per row, D=512 -> 2 elems/thread
// ---------------------------------------------------------------------------
__global__ __launch_bounds__(256) void ln_k(const float* __restrict__ x,
                                            const float* __restrict__ g,
                                            const float* __restrict__ b,
                                            float* __restrict__ o)
{
    const int row = blockIdx.x, tid = threadIdx.x;
    const float* xr = x + (size_t)row * D;
    float v0 = xr[tid], v1 = xr[tid + 256];
    __shared__ float red[256];
    red[tid] = v0 + v1;
    __syncthreads();
    for (int off = 128; off > 0; off >>= 1) {
        if (tid < off) red[tid] += red[tid + off];
        __syncthreads();
    }
    float mu = red[0] * (1.f / D);
    __syncthreads();
    float d0 = v0 - mu, d1 = v1 - mu;
    red[tid] = d0 * d0 + d1 * d1;
    __syncthreads();
    for (int off = 128; off > 0; off >>= 1) {
        if (tid < off) red[tid] += red[tid + off];
        __syncthreads();
    }
    float rs = rsqrtf(red[0] * (1.f / D) + EPS);
    float* orow = o + (size_t)row * D;
    orow[tid]       = d0 * rs * g[tid]       + b[tid];
    orow[tid + 256] = d1 * rs * g[tid + 256] + b[tid + 256];
}

// ---------------------------------------------------------------------------
// Tiled fp32 GEMM, 64x64 tile, 256 threads (16x16, 4x4 micro-tile), K=D=512.
// MODE 0: QKV projection. Bm = W[h][d][e] (H,D,HS); out scattered to (B,H,L,HS).
// MODE 1: MLP. Bm row-major (D,D); out = gelu(acc+bias) + outp (in-place h).
// MODE 2: FC.  Bm row-major (D,N);  out = acc + bias (N=513, bounds-checked).
// ---------------------------------------------------------------------------
template <int MODE>
__global__ __launch_bounds__(256) void gemm_k(const float* __restrict__ A,
                                              const float* __restrict__ Bm,
                                              const float* __restrict__ bias,
                                              float* __restrict__ outp,
                                              int M, int N)
{
    __shared__ float As[16][65];   // [kk][r]
    __shared__ float Bs[16][65];   // [kk][c]
    const int tid  = threadIdx.x;
    const int row0 = blockIdx.y * 64;
    const int col0 = blockIdx.x * 64;
    const int tx = tid & 15, ty = tid >> 4;
    float acc[4][4] = {};

    for (int k0 = 0; k0 < D; k0 += 16) {
#pragma unroll
        for (int i = 0; i < 4; ++i) {
            int idx = tid + i * 256;
            int r = idx >> 4, kk = idx & 15;
            float av = 0.f;
            if (row0 + r < M) av = A[(size_t)(row0 + r) * D + k0 + kk];
            As[kk][r] = av;
        }
#pragma unroll
        for (int i = 0; i < 4; ++i) {
            int idx = tid + i * 256;
            int c = idx & 63, kk = idx >> 6;
            float bv;
            if (MODE == 0) {
                // head = blockIdx.x (tile width == HS == 64), e = c
                bv = Bm[(size_t)blockIdx.x * D * HS + (size_t)(k0 + kk) * HS + c];
            } else if (MODE == 1) {
                bv = Bm[(size_t)(k0 + kk) * D + col0 + c];
            } else {
                bv = (col0 + c < N) ? Bm[(size_t)(k0 + kk) * N + col0 + c] : 0.f;
            }
            Bs[kk][c] = bv;
        }
        __syncthreads();
#pragma unroll
        for (int kk = 0; kk < 16; ++kk) {
            float a[4], b[4];
#pragma unroll
            for (int j = 0; j < 4; ++j) { a[j] = As[kk][ty * 4 + j]; b[j] = Bs[kk][tx * 4 + j]; }
#pragma unroll
            for (int i2 = 0; i2 < 4; ++i2)
#pragma unroll
                for (int j = 0; j < 4; ++j) acc[i2][j] += a[i2] * b[j];
        }
        __syncthreads();
    }

#pragma unroll
    for (int i = 0; i < 4; ++i) {
        int r = row0 + ty * 4 + i;
        if (r >= M) continue;
#pragma unroll
        for (int j = 0; j < 4; ++j) {
            int c = col0 + tx * 4 + j;
            float val = acc[i][j];
            if (MODE == 0) {
                int b_ = r / L, l = r % L;
                int head = c >> 6, e = c & 63;
                outp[(((size_t)b_ * H + head) * L + l) * HS + e] = val;
            } else if (MODE == 1) {
                float xv = val + bias[c];
                float gl = 0.5f * xv * (1.f + erff(xv * 0.70710678118654752f));
                outp[(size_t)r * D + c] = gl + outp[(size_t)r * D + c];
            } else {
                if (c < N) outp[(size_t)r * N + c] = val + bias[c];
            }
        }
    }
}

// ---------------------------------------------------------------------------
// Flash attention: one block per (b, h, q-tile of 64). 256 threads (16x16),
// 4x4 micro-tile on both QK^T and PV. Online softmax, fused residual add.
// LDS layouts: Qs/Ks are [e][row] (transposed, so S-phase reads are float4
// over the row dim); Vs is [m][e] row-major; Ps is [q][m] row-major.
// Pad 68 keeps float4 alignment; bank aliasing is 2-way (free) on all hot
// reads (stride-4-float patterns over 16 lanes).
// ---------------------------------------------------------------------------
__global__ __launch_bounds__(256) void fattn_k(const float* __restrict__ q,
                                               const float* __restrict__ k,
                                               const float* __restrict__ v,
                                               float* __restrict__ hbuf)
{
    __shared__ float Qs[64][68];   // [e][q]
    __shared__ float Ks[64][68];   // [e][m]
    __shared__ float Vs[64][68];   // [m][e]
    __shared__ float Ps[64][68];   // [q][m]

    const int bx  = blockIdx.x;
    const int bh  = bx / 9;              // b*H + h
    const int qt  = 8 - (bx % 9);        // big tiles dispatched first
    const int q0  = qt * 64;
    const int tid = threadIdx.x;
    const int tx  = tid & 15, ty = tid >> 4;

    // ---- load Q tile (transposed into Qs[e][r]) ----
    {
        const int r = tid & 63, e0 = (tid >> 6) * 16;
        const int qrow = q0 + r;
        if (qrow < L) {
            const float* src = q + ((size_t)bh * L + qrow) * HS + e0;
#pragma unroll
            for (int e = 0; e < 16; e += 4) {
                float4 f4 = *(const float4*)(src + e);
                Qs[e0 + e][r]     = f4.x;
                Qs[e0 + e + 1][r] = f4.y;
                Qs[e0 + e + 2][r] = f4.z;
                Qs[e0 + e + 3][r] = f4.w;
            }
        } else {
#pragma unroll
            for (int e = 0; e < 16; ++e) Qs[e0 + e][r] = 0.f;
        }
    }

    float m_run[4], l_run[4], o[4][4];
#pragma unroll
    for (int i = 0; i < 4; ++i) {
        m_run[i] = -INFINITY;
        l_run[i] = 0.f;
#pragma unroll
        for (int j = 0; j < 4; ++j) o[i][j] = 0.f;
    }

    const float scale = 0.125f;          // HS^-0.5
    const int mmax = min(L - 1, q0 + 63);
    const int n_mt = mmax / 64 + 1;

    for (int t = 0; t < n_mt; ++t) {
        const int m0 = t * 64;
        // ---- load K (transposed) + V (row-major) ----
        {
            const int r = tid & 63, e0 = (tid >> 6) * 16;
            const int mrow = m0 + r;
            if (mrow < L) {   // rows >= L: stale finite data, masked below
                const float* ksrc = k + ((size_t)bh * L + mrow) * HS + e0;
                const float* vsrc = v + ((size_t)bh * L + mrow) * HS + e0;
#pragma unroll
                for (int e = 0; e < 16; e += 4) {
                    float4 kf = *(const float4*)(ksrc + e);
                    Ks[e0 + e][r]     = kf.x;
                    Ks[e0 + e + 1][r] = kf.y;
                    Ks[e0 + e + 2][r] = kf.z;
                    Ks[e0 + e + 3][r] = kf.w;
                    *(float4*)&Vs[r][e0 + e] = *(const float4*)(vsrc + e);
                }
            }
        }
        __syncthreads();

        // ---- S tile: acc[i][j] = sum_e Q[q0+ty*4+i][e] * K[m0+tx*4+j][e] ----
        float acc[4][4] = {};
#pragma unroll 4
        for (int e = 0; e < 64; ++e) {
            float4 a4 = *(const float4*)&Qs[e][ty * 4];
            float4 b4 = *(const float4*)&Ks[e][tx * 4];
            acc[0][0] += a4.x * b4.x; acc[0][1] += a4.x * b4.y; acc[0][2] += a4.x * b4.z; acc[0][3] += a4.x * b4.w;
            acc[1][0] += a4.y * b4.x; acc[1][1] += a4.y * b4.y; acc[1][2] += a4.y * b4.z; acc[1][3] += a4.y * b4.w;
            acc[2][0] += a4.z * b4.x; acc[2][1] += a4.z * b4.y; acc[2][2] += a4.z * b4.z; acc[2][3] += a4.z * b4.w;
            acc[3][0] += a4.w * b4.x; acc[3][1] += a4.w * b4.y; acc[3][2] += a4.w * b4.z; acc[3][3] += a4.w * b4.w;
        }

        // ---- mask + online softmax (rows spread over tx lanes) ----
#pragma unroll
        for (int i = 0; i < 4; ++i) {
            const int qrow = q0 + ty * 4 + i;
            float rmax = -INFINITY;
#pragma unroll
            for (int j = 0; j < 4; ++j) {
                const int mcol = m0 + tx * 4 + j;
                float s = acc[i][j] * scale;
                if (mcol > qrow || mcol >= L) s = -INFINITY;
                acc[i][j] = s;
                rmax = fmaxf(rmax, s);
            }
            rmax = fmaxf(rmax, __shfl_xor(rmax, 1));
            rmax = fmaxf(rmax, __shfl_xor(rmax, 2));
            rmax = fmaxf(rmax, __shfl_xor(rmax, 4));
            rmax = fmaxf(rmax, __shfl_xor(rmax, 8));
            const float mnew = fmaxf(m_run[i], rmax);
            const float f = __expf(m_run[i] - mnew);   // NaN only for q>=L rows (guarded at write)
            float psum = 0.f;
#pragma unroll
            for (int j = 0; j < 4; ++j) {
                float p = __expf(acc[i][j] - mnew);
                acc[i][j] = p;
                psum += p;
            }
            psum += __shfl_xor(psum, 1);
            psum += __shfl_xor(psum, 2);
            psum += __shfl_xor(psum, 4);
            psum += __shfl_xor(psum, 8);
            l_run[i] = l_run[i] * f + psum;
            m_run[i] = mnew;
#pragma unroll
            for (int j = 0; j < 4; ++j) o[i][j] *= f;
            *(float4*)&Ps[ty * 4 + i][tx * 4] =
                make_float4(acc[i][0], acc[i][1], acc[i][2], acc[i][3]);
        }
        __syncthreads();

        // ---- PV: o[i][j] += sum_m P[q][m] * V[m][e=tx*4+j] ----
#pragma unroll 4
        for (int m = 0; m < 64; ++m) {
            float4 b4 = *(const float4*)&Vs[m][tx * 4];
#pragma unroll
            for (int i = 0; i < 4; ++i) {
                float p = Ps[ty * 4 + i][m];
                o[i][0] += p * b4.x;
                o[i][1] += p * b4.y;
                o[i][2] += p * b4.z;
                o[i][3] += p * b4.w;
            }
        }
        __syncthreads();   // protect Ks/Vs before next tile's load
    }

    // ---- epilogue: y = o / l, fused residual into h ----
    const int b_ = bh / H, hh = bh % H;
#pragma unroll
    for (int i = 0; i < 4; ++i) {
        const int qrow = q0 + ty * 4 + i;
        if (qrow >= L) continue;
        const float inv = 1.f / l_run[i];
        float* dst = hbuf + ((size_t)b_ * L + qrow) * D + hh * HS + tx * 4;
        float4 hv = *(const float4*)dst;
        hv.x += o[i][0] * inv;
        hv.y += o[i][1] * inv;
        hv.z += o[i][2] * inv;
        hv.w += o[i][3] * inv;
        *(float4*)dst = hv;
    }
}

// ---------------------------------------------------------------------------
extern "C" void kernel_launch(void* const* d_in, const int* in_sizes, int n_in,
                              void* d_out, int out_size, void* d_ws, size_t ws_size,
                              hipStream_t stream)
{
    const int*   x    = (const int*)d_in[0];
    const float* emb  = (const float*)d_in[1];
    const float* pos  = (const float*)d_in[2];
    const float* Wq   = (const float*)d_in[3];
    const float* Wk   = (const float*)d_in[4];
    const float* Wv   = (const float*)d_in[5];
    const float* ln1g = (const float*)d_in[6];
    const float* ln1b = (const float*)d_in[7];
    const float* ln2g = (const float*)d_in[8];
    const float* ln2b = (const float*)d_in[9];
    const float* mlpW = (const float*)d_in[10];
    const float* mlpb = (const float*)d_in[11];
    const float* fcW  = (const float*)d_in[12];
    const float* fcb  = (const float*)d_in[13];
    float* out = (float*)d_out;

    float* h  = (float*)d_ws;
    float* xn = h  + (size_t)BL * D;
    float* q  = xn + (size_t)BL * D;
    float* k  = q  + (size_t)BL * D;
    float* v  = k  + (size_t)BL * D;

    embed_k<<<BL, 256, 0, stream>>>(x, emb, pos, h);

    dim3 g8(8, 65);   // 512/64 cols, ceil(4104/64) rows
    dim3 g9(9, 65);   // ceil(513/64) cols

    for (int i = 0; i < NL; ++i) {
        ln_k<<<BL, 256, 0, stream>>>(h, ln1g + i * D, ln1b + i * D, xn);
        gemm_k<0><<<g8, 256, 0, stream>>>(xn, Wq + (size_t)i * H * D * HS, nullptr, q, BL, D);
        gemm_k<0><<<g8, 256, 0, stream>>>(xn, Wk + (size_t)i * H * D * HS, nullptr, k, BL, D);
        gemm_k<0><<<g8, 256, 0, stream>>>(xn, Wv + (size_t)i * H * D * HS, nullptr, v, BL, D);
        fattn_k<<<B * H * 9, 256, 0, stream>>>(q, k, v, h);
        ln_k<<<BL, 256, 0, stream>>>(h, ln2g + i * D, ln2b + i * D, xn);
        gemm_k<1><<<g8, 256, 0, stream>>>(xn, mlpW + (size_t)i * D * D, mlpb + i * D, h, BL, D);
    }
    gemm_k<2><<<g9, 256, 0, stream>>>(h, fcW, fcb, out, BL, V);
}

// Round 5
// 932.467 us; speedup vs baseline: 5.5308x; 2.7552x over previous
//
#include <hip/hip_runtime.h>
#include <hip/hip_bf16.h>
#include <math.h>

#define B 8
#define L 513
#define D 512
#define H 8
#define HS 64
#define V 513
#define NL 6
#define BL (B * L)          // 4104
#define EPS 1e-5f

typedef __attribute__((ext_vector_type(8))) short bf16x8;   // 8 bf16 (4 VGPRs)
typedef __attribute__((ext_vector_type(4))) float f32x4;    // MFMA accumulator

__device__ inline ushort f2b(float f) {
    __hip_bfloat16 h = __float2bfloat16(f);
    return *reinterpret_cast<ushort*>(&h);
}

// ---------------------------------------------------------------------------
// embed + positional: h[b,l,:] = embed[x[b,l],:] + pos_embed[l,:]
// ---------------------------------------------------------------------------
__global__ __launch_bounds__(256) void embed_k(const int* __restrict__ x,
                                               const float* __restrict__ emb,
                                               const float* __restrict__ pos,
                                               float* __restrict__ hbuf)
{
    int row = blockIdx.x;
    int l   = row % L;
    int tok = x[row];
    const float* er = emb + (size_t)tok * D;
    const float* pr = pos + (size_t)l * D;
    float* hr = hbuf + (size_t)row * D;
    for (int d = threadIdx.x; d < D; d += 256)
        hr[d] = er[d] + pr[d];
}

// ---------------------------------------------------------------------------
// LayerNorm: one block per row; OUTPUT IS BF16 (feeds MFMA GEMMs).
// ---------------------------------------------------------------------------
__global__ __launch_bounds__(256) void ln_k(const float* __restrict__ x,
                                            const float* __restrict__ g,
                                            const float* __restrict__ b,
                                            ushort* __restrict__ o)
{
    const int row = blockIdx.x, tid = threadIdx.x;
    const float* xr = x + (size_t)row * D;
    float v0 = xr[tid], v1 = xr[tid + 256];
    __shared__ float red[256];
    red[tid] = v0 + v1;
    __syncthreads();
    for (int off = 128; off > 0; off >>= 1) {
        if (tid < off) red[tid] += red[tid + off];
        __syncthreads();
    }
    float mu = red[0] * (1.f / D);
    __syncthreads();
    float d0 = v0 - mu, d1 = v1 - mu;
    red[tid] = d0 * d0 + d1 * d1;
    __syncthreads();
    for (int off = 128; off > 0; off >>= 1) {
        if (tid < off) red[tid] += red[tid + off];
        __syncthreads();
    }
    float rs = rsqrtf(red[0] * (1.f / D) + EPS);
    ushort* orow = o + (size_t)row * D;
    orow[tid]       = f2b(d0 * rs * g[tid]       + b[tid]);
    orow[tid + 256] = f2b(d1 * rs * g[tid + 256] + b[tid + 256]);
}

// ---------------------------------------------------------------------------
// h (fp32) -> bf16, for the FC input
// ---------------------------------------------------------------------------
__global__ __launch_bounds__(256) void h2bf_k(const float* __restrict__ h,
                                              ushort* __restrict__ o)
{
    int idx = blockIdx.x * 256 + threadIdx.x;      // one float4 per thread
    float4 f = *(const float4*)(h + (size_t)idx * 4);
    ushort4 u;
    u.x = f2b(f.x); u.y = f2b(f.y); u.z = f2b(f.z); u.w = f2b(f.w);
    *(ushort4*)(o + (size_t)idx * 4) = u;
}

// ---------------------------------------------------------------------------
// Weight pack/cast kernels (run every launch; ~7 us total).
// QKV: W[sel][i][h][d][e] (D,HS per head) -> Wp[i][n][d] bf16, n = sel*512+h*64+e
// ---------------------------------------------------------------------------
__global__ __launch_bounds__(256) void cvt_qkv_k(const float* __restrict__ Wq,
                                                 const float* __restrict__ Wk,
                                                 const float* __restrict__ Wv,
                                                 ushort* __restrict__ Wp)
{
    const int dc = blockIdx.x;                 // d-tile (8)
    const int i  = blockIdx.y / H, h = blockIdx.y % H;
    const int sel = blockIdx.z;
    const float* W = (sel == 0) ? Wq : (sel == 1) ? Wk : Wv;
    const float* src = W + ((size_t)i * H + h) * D * HS + (size_t)dc * 64 * HS;
    __shared__ float T[64][65];
    const int tid = threadIdx.x;
#pragma unroll
    for (int it = 0; it < 4; ++it) {
        int idx = tid + it * 256;              // 0..1023
        int r = idx >> 4, e4 = (idx & 15) * 4; // r = d-local, e4 = head col
        float4 f = *(const float4*)(src + (size_t)r * HS + e4);
        T[r][e4] = f.x; T[r][e4 + 1] = f.y; T[r][e4 + 2] = f.z; T[r][e4 + 3] = f.w;
    }
    __syncthreads();
    ushort* dst = Wp + (size_t)i * 1536 * 512 + (size_t)(sel * 512 + h * 64) * 512 + dc * 64;
#pragma unroll
    for (int it = 0; it < 4; ++it) {
        int idx = tid + it * 256;
        int e = idx >> 4, d4 = (idx & 15) * 4;
        ushort4 u;
        u.x = f2b(T[d4][e]); u.y = f2b(T[d4 + 1][e]);
        u.z = f2b(T[d4 + 2][e]); u.w = f2b(T[d4 + 3][e]);
        *(ushort4*)(dst + (size_t)e * 512 + d4) = u;
    }
}

// mlp_W[i][k][n] (D,D) -> Wt[i][n][k] bf16
__global__ __launch_bounds__(256) void cvt_mlp_k(const float* __restrict__ Wm,
                                                 ushort* __restrict__ Wt)
{
    const int nt = blockIdx.x, kt = blockIdx.y, i = blockIdx.z;
    const float* src = Wm + (size_t)i * D * D;
    __shared__ float T[64][65];
    const int tid = threadIdx.x;
#pragma unroll
    for (int it = 0; it < 4; ++it) {
        int idx = tid + it * 256;
        int r = idx >> 4, e4 = (idx & 15) * 4;     // r = k-local, e = n-local
        float4 f = *(const float4*)(src + (size_t)(kt * 64 + r) * D + nt * 64 + e4);
        T[r][e4] = f.x; T[r][e4 + 1] = f.y; T[r][e4 + 2] = f.z; T[r][e4 + 3] = f.w;
    }
    __syncthreads();
    ushort* dst = Wt + (size_t)i * D * D + (size_t)(nt * 64) * D + kt * 64;
#pragma unroll
    for (int it = 0; it < 4; ++it) {
        int idx = tid + it * 256;
        int e = idx >> 4, k4 = (idx & 15) * 4;
        ushort4 u;
        u.x = f2b(T[k4][e]); u.y = f2b(T[k4 + 1][e]);
        u.z = f2b(T[k4 + 2][e]); u.w = f2b(T[k4 + 3][e]);
        *(ushort4*)(dst + (size_t)e * D + k4) = u;
    }
}

// fc_W[k][n] (512,513) -> Wt[n][k] bf16, n padded to 576 with zeros
__global__ __launch_bounds__(256) void cvt_fc_k(const float* __restrict__ Wf,
                                                ushort* __restrict__ Wt)
{
    const int nt = blockIdx.x, kt = blockIdx.y;    // 9 x 8
    __shared__ float T[64][65];
    const int tid = threadIdx.x;
#pragma unroll
    for (int it = 0; it < 4; ++it) {
        int idx = tid + it * 256;
        int r = idx >> 4, e4 = (idx & 15) * 4;
#pragma unroll
        for (int j = 0; j < 4; ++j) {
            int n = nt * 64 + e4 + j;
            T[r][e4 + j] = (n < V) ? Wf[(size_t)(kt * 64 + r) * V + n] : 0.f;
        }
    }
    __syncthreads();
    ushort* dst = Wt + (size_t)(nt * 64) * 512 + kt * 64;
#pragma unroll
    for (int it = 0; it < 4; ++it) {
        int idx = tid + it * 256;
        int e = idx >> 4, k4 = (idx & 15) * 4;
        ushort4 u;
        u.x = f2b(T[k4][e]); u.y = f2b(T[k4 + 1][e]);
        u.z = f2b(T[k4 + 2][e]); u.w = f2b(T[k4 + 3][e]);
        *(ushort4*)(dst + (size_t)e * 512 + k4) = u;
    }
}

// ---------------------------------------------------------------------------
// bf16 MFMA GEMM: C[M x Ncols] = A[M x 512] * Bt[Ncols x 512]^T
// 64x64 tile, 4 waves (each 32x32 = 2x2 frags of 16x16), BK=64, K=512.
// LDS rows padded to 72 bf16 (144 B): frag ds_read_b128 and staging writes
// both land at the 8-words-per-bank floor (2-way max aliasing).
// MODE 0: QKV (Ncols=1536): scatter to q/k/v as (B,H,L,HS) fp32.
// MODE 1: MLP (Ncols=512):  out0 = gelu(acc+bias) + out0 (in-place h).
// MODE 2: FC  (Ncols=576p): out0[r*V+c] = acc + bias[c], c < V.
// ---------------------------------------------------------------------------
template <int MODE>
__global__ __launch_bounds__(256) void mgemm_k(const ushort* __restrict__ A,
                                               const ushort* __restrict__ Bt,
                                               const float* __restrict__ bias,
                                               float* __restrict__ out0,
                                               float* __restrict__ out1,
                                               float* __restrict__ out2)
{
    __shared__ ushort As[64][72];
    __shared__ ushort Bs[64][72];
    const int tid  = threadIdx.x;
    const int wave = tid >> 6, lane = tid & 63;
    const int row0 = blockIdx.y * 64;
    const int col0 = blockIdx.x * 64;
    const int wr = (wave >> 1) * 32, wc = (wave & 1) * 32;
    const int frow = lane & 15;          // fragment row/col within 16
    const int kb   = lane >> 4;          // k-block: 8 bf16 at kb*8

    f32x4 acc[2][2] = {};

    for (int k0 = 0; k0 < 512; k0 += 64) {
#pragma unroll
        for (int it = 0; it < 2; ++it) {
            int idx = tid + it * 256;        // 512 slots of 8 bf16
            int r = idx >> 3, kc = idx & 7;
            uint4 av = make_uint4(0u, 0u, 0u, 0u);
            if (row0 + r < BL)
                av = *(const uint4*)(A + (size_t)(row0 + r) * 512 + k0 + kc * 8);
            *(uint4*)&As[r][kc * 8] = av;
            uint4 bv = *(const uint4*)(Bt + (size_t)(col0 + r) * 512 + k0 + kc * 8);
            *(uint4*)&Bs[r][kc * 8] = bv;
        }
        __syncthreads();
#pragma unroll
        for (int ks = 0; ks < 2; ++ks) {     // two K=32 sub-steps
            bf16x8 a[2], b[2];
#pragma unroll
            for (int f = 0; f < 2; ++f) {
                a[f] = *(const bf16x8*)&As[wr + f * 16 + frow][ks * 32 + kb * 8];
                b[f] = *(const bf16x8*)&Bs[wc + f * 16 + frow][ks * 32 + kb * 8];
            }
#pragma unroll
            for (int fi = 0; fi < 2; ++fi)
#pragma unroll
                for (int fj = 0; fj < 2; ++fj)
                    acc[fi][fj] = __builtin_amdgcn_mfma_f32_16x16x32_bf16(
                        a[fi], b[fj], acc[fi][fj], 0, 0, 0);
        }
        __syncthreads();
    }

    // C frag layout: col = lane&15, row = (lane>>4)*4 + reg   [m89/m91]
    const int rbase = row0 + wr + (lane >> 4) * 4;
    const int cbase = col0 + wc + (lane & 15);
#pragma unroll
    for (int fi = 0; fi < 2; ++fi) {
#pragma unroll
        for (int fj = 0; fj < 2; ++fj) {
            const int c = cbase + fj * 16;
#pragma unroll
            for (int rg = 0; rg < 4; ++rg) {
                const int r = rbase + fi * 16 + rg;
                if (r >= BL) continue;
                float val = acc[fi][fj][rg];
                if (MODE == 0) {
                    int buf = c >> 9, cc = c & 511;
                    int b_ = r / L, l = r % L;
                    int head = cc >> 6, e = cc & 63;
                    float* dst = (buf == 0) ? out0 : (buf == 1) ? out1 : out2;
                    dst[(((size_t)b_ * H + head) * L + l) * HS + e] = val;
                } else if (MODE == 1) {
                    float xv = val + bias[c];
                    float gl = 0.5f * xv * (1.f + erff(xv * 0.70710678118654752f));
                    out0[(size_t)r * D + c] = gl + out0[(size_t)r * D + c];
                } else {
                    if (c < V) out0[(size_t)r * V + c] = val + bias[c];
                }
            }
        }
    }
}

// ---------------------------------------------------------------------------
// Flash attention (unchanged from Round 4): one block per (b,h,q-tile of 64).
// ---------------------------------------------------------------------------
__global__ __launch_bounds__(256) void fattn_k(const float* __restrict__ q,
                                               const float* __restrict__ k,
                                               const float* __restrict__ v,
                                               float* __restrict__ hbuf)
{
    __shared__ float Qs[64][68];   // [e][q]
    __shared__ float Ks[64][68];   // [e][m]
    __shared__ float Vs[64][68];   // [m][e]
    __shared__ float Ps[64][68];   // [q][m]

    const int bx  = blockIdx.x;
    const int bh  = bx / 9;
    const int qt  = 8 - (bx % 9);
    const int q0  = qt * 64;
    const int tid = threadIdx.x;
    const int tx  = tid & 15, ty = tid >> 4;

    {
        const int r = tid & 63, e0 = (tid >> 6) * 16;
        const int qrow = q0 + r;
        if (qrow < L) {
            const float* src = q + ((size_t)bh * L + qrow) * HS + e0;
#pragma unroll
            for (int e = 0; e < 16; e += 4) {
                float4 f4 = *(const float4*)(src + e);
                Qs[e0 + e][r]     = f4.x;
                Qs[e0 + e + 1][r] = f4.y;
                Qs[e0 + e + 2][r] = f4.z;
                Qs[e0 + e + 3][r] = f4.w;
            }
        } else {
#pragma unroll
            for (int e = 0; e < 16; ++e) Qs[e0 + e][r] = 0.f;
        }
    }

    float m_run[4], l_run[4], o[4][4];
#pragma unroll
    for (int i = 0; i < 4; ++i) {
        m_run[i] = -INFINITY;
        l_run[i] = 0.f;
#pragma unroll
        for (int j = 0; j < 4; ++j) o[i][j] = 0.f;
    }

    const float scale = 0.125f;
    const int mmax = min(L - 1, q0 + 63);
    const int n_mt = mmax / 64 + 1;

    for (int t = 0; t < n_mt; ++t) {
        const int m0 = t * 64;
        {
            const int r = tid & 63, e0 = (tid >> 6) * 16;
            const int mrow = m0 + r;
            if (mrow < L) {
                const float* ksrc = k + ((size_t)bh * L + mrow) * HS + e0;
                const float* vsrc = v + ((size_t)bh * L + mrow) * HS + e0;
#pragma unroll
                for (int e = 0; e < 16; e += 4) {
                    float4 kf = *(const float4*)(ksrc + e);
                    Ks[e0 + e][r]     = kf.x;
                    Ks[e0 + e + 1][r] = kf.y;
                    Ks[e0 + e + 2][r] = kf.z;
                    Ks[e0 + e + 3][r] = kf.w;
                    *(float4*)&Vs[r][e0 + e] = *(const float4*)(vsrc + e);
                }
            }
        }
        __syncthreads();

        float acc[4][4] = {};
#pragma unroll 4
        for (int e = 0; e < 64; ++e) {
            float4 a4 = *(const float4*)&Qs[e][ty * 4];
            float4 b4 = *(const float4*)&Ks[e][tx * 4];
            acc[0][0] += a4.x * b4.x; acc[0][1] += a4.x * b4.y; acc[0][2] += a4.x * b4.z; acc[0][3] += a4.x * b4.w;
            acc[1][0] += a4.y * b4.x; acc[1][1] += a4.y * b4.y; acc[1][2] += a4.y * b4.z; acc[1][3] += a4.y * b4.w;
            acc[2][0] += a4.z * b4.x; acc[2][1] += a4.z * b4.y; acc[2][2] += a4.z * b4.z; acc[2][3] += a4.z * b4.w;
            acc[3][0] += a4.w * b4.x; acc[3][1] += a4.w * b4.y; acc[3][2] += a4.w * b4.z; acc[3][3] += a4.w * b4.w;
        }

#pragma unroll
        for (int i = 0; i < 4; ++i) {
            const int qrow = q0 + ty * 4 + i;
            float rmax = -INFINITY;
#pragma unroll
            for (int j = 0; j < 4; ++j) {
                const int mcol = m0 + tx * 4 + j;
                float s = acc[i][j] * scale;
                if (mcol > qrow || mcol >= L) s = -INFINITY;
                acc[i][j] = s;
                rmax = fmaxf(rmax, s);
            }
            rmax = fmaxf(rmax, __shfl_xor(rmax, 1));
            rmax = fmaxf(rmax, __shfl_xor(rmax, 2));
            rmax = fmaxf(rmax, __shfl_xor(rmax, 4));
            rmax = fmaxf(rmax, __shfl_xor(rmax, 8));
            const float mnew = fmaxf(m_run[i], rmax);
            const float f = __expf(m_run[i] - mnew);
            float psum = 0.f;
#pragma unroll
            for (int j = 0; j < 4; ++j) {
                float p = __expf(acc[i][j] - mnew);
                acc[i][j] = p;
                psum += p;
            }
            psum += __shfl_xor(psum, 1);
            psum += __shfl_xor(psum, 2);
            psum += __shfl_xor(psum, 4);
            psum += __shfl_xor(psum, 8);
            l_run[i] = l_run[i] * f + psum;
            m_run[i] = mnew;
#pragma unroll
            for (int j = 0; j < 4; ++j) o[i][j] *= f;
            *(float4*)&Ps[ty * 4 + i][tx * 4] =
                make_float4(acc[i][0], acc[i][1], acc[i][2], acc[i][3]);
        }
        __syncthreads();

#pragma unroll 4
        for (int m = 0; m < 64; ++m) {
            float4 b4 = *(const float4*)&Vs[m][tx * 4];
#pragma unroll
            for (int i = 0; i < 4; ++i) {
                float p = Ps[ty * 4 + i][m];
                o[i][0] += p * b4.x;
                o[i][1] += p * b4.y;
                o[i][2] += p * b4.z;
                o[i][3] += p * b4.w;
            }
        }
        __syncthreads();
    }

    const int b_ = bh / H, hh = bh % H;
#pragma unroll
    for (int i = 0; i < 4; ++i) {
        const int qrow = q0 + ty * 4 + i;
        if (qrow >= L) continue;
        const float inv = 1.f / l_run[i];
        float* dst = hbuf + ((size_t)b_ * L + qrow) * D + hh * HS + tx * 4;
        float4 hv = *(const float4*)dst;
        hv.x += o[i][0] * inv;
        hv.y += o[i][1] * inv;
        hv.z += o[i][2] * inv;
        hv.w += o[i][3] * inv;
        *(float4*)dst = hv;
    }
}

// ---------------------------------------------------------------------------
extern "C" void kernel_launch(void* const* d_in, const int* in_sizes, int n_in,
                              void* d_out, int out_size, void* d_ws, size_t ws_size,
                              hipStream_t stream)
{
    const int*   x    = (const int*)d_in[0];
    const float* emb  = (const float*)d_in[1];
    const float* pos  = (const float*)d_in[2];
    const float* Wq   = (const float*)d_in[3];
    const float* Wk   = (const float*)d_in[4];
    const float* Wv   = (const float*)d_in[5];
    const float* ln1g = (const float*)d_in[6];
    const float* ln1b = (const float*)d_in[7];
    const float* ln2g = (const float*)d_in[8];
    const float* ln2b = (const float*)d_in[9];
    const float* mlpW = (const float*)d_in[10];
    const float* mlpb = (const float*)d_in[11];
    const float* fcW  = (const float*)d_in[12];
    const float* fcb  = (const float*)d_in[13];
    float* out = (float*)d_out;

    // workspace layout (fp32 first, then bf16) — all 16B aligned
    char* ws = (char*)d_ws;
    float* h  = (float*)ws;                       ws += (size_t)BL * D * 4;
    float* q  = (float*)ws;                       ws += (size_t)BL * D * 4;
    float* k  = (float*)ws;                       ws += (size_t)BL * D * 4;
    float* v  = (float*)ws;                       ws += (size_t)BL * D * 4;
    ushort* xnb  = (ushort*)ws;                   ws += (size_t)BL * D * 2;
    ushort* hb   = (ushort*)ws;                   ws += (size_t)BL * D * 2;
    ushort* Wp   = (ushort*)ws;                   ws += (size_t)NL * 1536 * 512 * 2;
    ushort* Wtm  = (ushort*)ws;                   ws += (size_t)NL * D * D * 2;
    ushort* Wtf  = (ushort*)ws;                   ws += (size_t)576 * 512 * 2;

    // weight pack/cast (every launch; graph-safe)
    cvt_qkv_k<<<dim3(8, NL * H, 3), 256, 0, stream>>>(Wq, Wk, Wv, Wp);
    cvt_mlp_k<<<dim3(8, 8, NL), 256, 0, stream>>>(mlpW, Wtm);
    cvt_fc_k<<<dim3(9, 8), 256, 0, stream>>>(fcW, Wtf);

    embed_k<<<BL, 256, 0, stream>>>(x, emb, pos, h);

    for (int i = 0; i < NL; ++i) {
        ln_k<<<BL, 256, 0, stream>>>(h, ln1g + i * D, ln1b + i * D, xnb);
        mgemm_k<0><<<dim3(24, 65), 256, 0, stream>>>(
            xnb, Wp + (size_t)i * 1536 * 512, nullptr, q, k, v);
        fattn_k<<<B * H * 9, 256, 0, stream>>>(q, k, v, h);
        ln_k<<<BL, 256, 0, stream>>>(h, ln2g + i * D, ln2b + i * D, xnb);
        mgemm_k<1><<<dim3(8, 65), 256, 0, stream>>>(
            xnb, Wtm + (size_t)i * D * D, mlpb + i * D, h, nullptr, nullptr);
    }
    h2bf_k<<<BL * D / 1024, 256, 0, stream>>>(h, hb);
    mgemm_k<2><<<dim3(9, 65), 256, 0, stream>>>(hb, Wtf, fcb, out, nullptr, nullptr);
}

// Round 6
// 646.015 us; speedup vs baseline: 7.9833x; 1.4434x over previous
//
#include <hip/hip_runtime.h>
#include <hip/hip_bf16.h>
#include <math.h>

#define B 8
#define L 513
#define D 512
#define H 8
#define HS 64
#define V 513
#define NL 6
#define BL (B * L)          // 4104
#define LP 576              // padded L for vT
#define EPS 1e-5f

typedef __attribute__((ext_vector_type(8))) short bf16x8;   // 8 bf16 (4 VGPRs)
typedef __attribute__((ext_vector_type(4))) float f32x4;    // MFMA accumulator

__device__ inline ushort f2b(float f) {
    __hip_bfloat16 h = __float2bfloat16(f);
    return *reinterpret_cast<ushort*>(&h);
}

// ---------------------------------------------------------------------------
// embed + positional
// ---------------------------------------------------------------------------
__global__ __launch_bounds__(256) void embed_k(const int* __restrict__ x,
                                               const float* __restrict__ emb,
                                               const float* __restrict__ pos,
                                               float* __restrict__ hbuf)
{
    int row = blockIdx.x;
    int l   = row % L;
    int tok = x[row];
    const float* er = emb + (size_t)tok * D;
    const float* pr = pos + (size_t)l * D;
    float* hr = hbuf + (size_t)row * D;
    for (int d = threadIdx.x; d < D; d += 256)
        hr[d] = er[d] + pr[d];
}

// ---------------------------------------------------------------------------
// LayerNorm: one block per row; OUTPUT IS BF16 (feeds MFMA GEMMs).
// ---------------------------------------------------------------------------
__global__ __launch_bounds__(256) void ln_k(const float* __restrict__ x,
                                            const float* __restrict__ g,
                                            const float* __restrict__ b,
                                            ushort* __restrict__ o)
{
    const int row = blockIdx.x, tid = threadIdx.x;
    const float* xr = x + (size_t)row * D;
    float v0 = xr[tid], v1 = xr[tid + 256];
    __shared__ float red[256];
    red[tid] = v0 + v1;
    __syncthreads();
    for (int off = 128; off > 0; off >>= 1) {
        if (tid < off) red[tid] += red[tid + off];
        __syncthreads();
    }
    float mu = red[0] * (1.f / D);
    __syncthreads();
    float d0 = v0 - mu, d1 = v1 - mu;
    red[tid] = d0 * d0 + d1 * d1;
    __syncthreads();
    for (int off = 128; off > 0; off >>= 1) {
        if (tid < off) red[tid] += red[tid + off];
        __syncthreads();
    }
    float rs = rsqrtf(red[0] * (1.f / D) + EPS);
    ushort* orow = o + (size_t)row * D;
    orow[tid]       = f2b(d0 * rs * g[tid]       + b[tid]);
    orow[tid + 256] = f2b(d1 * rs * g[tid + 256] + b[tid + 256]);
}

// ---------------------------------------------------------------------------
// h (fp32) -> bf16, for the FC input
// ---------------------------------------------------------------------------
__global__ __launch_bounds__(256) void h2bf_k(const float* __restrict__ h,
                                              ushort* __restrict__ o)
{
    int idx = blockIdx.x * 256 + threadIdx.x;
    float4 f = *(const float4*)(h + (size_t)idx * 4);
    ushort4 u;
    u.x = f2b(f.x); u.y = f2b(f.y); u.z = f2b(f.z); u.w = f2b(f.w);
    *(ushort4*)(o + (size_t)idx * 4) = u;
}

// ---------------------------------------------------------------------------
// Weight pack/cast kernels.
// QKV: W[sel][i][h][d][e] -> Wp[i][n][d] bf16, n = sel*512 + h*64 + e
// ---------------------------------------------------------------------------
__global__ __launch_bounds__(256) void cvt_qkv_k(const float* __restrict__ Wq,
                                                 const float* __restrict__ Wk,
                                                 const float* __restrict__ Wv,
                                                 ushort* __restrict__ Wp)
{
    const int dc = blockIdx.x;
    const int i  = blockIdx.y / H, h = blockIdx.y % H;
    const int sel = blockIdx.z;
    const float* W = (sel == 0) ? Wq : (sel == 1) ? Wk : Wv;
    const float* src = W + ((size_t)i * H + h) * D * HS + (size_t)dc * 64 * HS;
    __shared__ float T[64][65];
    const int tid = threadIdx.x;
#pragma unroll
    for (int it = 0; it < 4; ++it) {
        int idx = tid + it * 256;
        int r = idx >> 4, e4 = (idx & 15) * 4;
        float4 f = *(const float4*)(src + (size_t)r * HS + e4);
        T[r][e4] = f.x; T[r][e4 + 1] = f.y; T[r][e4 + 2] = f.z; T[r][e4 + 3] = f.w;
    }
    __syncthreads();
    ushort* dst = Wp + (size_t)i * 1536 * 512 + (size_t)(sel * 512 + h * 64) * 512 + dc * 64;
#pragma unroll
    for (int it = 0; it < 4; ++it) {
        int idx = tid + it * 256;
        int e = idx >> 4, d4 = (idx & 15) * 4;
        ushort4 u;
        u.x = f2b(T[d4][e]); u.y = f2b(T[d4 + 1][e]);
        u.z = f2b(T[d4 + 2][e]); u.w = f2b(T[d4 + 3][e]);
        *(ushort4*)(dst + (size_t)e * 512 + d4) = u;
    }
}

// mlp_W[i][k][n] (D,D) -> Wt[i][n][k] bf16
__global__ __launch_bounds__(256) void cvt_mlp_k(const float* __restrict__ Wm,
                                                 ushort* __restrict__ Wt)
{
    const int nt = blockIdx.x, kt = blockIdx.y, i = blockIdx.z;
    const float* src = Wm + (size_t)i * D * D;
    __shared__ float T[64][65];
    const int tid = threadIdx.x;
#pragma unroll
    for (int it = 0; it < 4; ++it) {
        int idx = tid + it * 256;
        int r = idx >> 4, e4 = (idx & 15) * 4;
        float4 f = *(const float4*)(src + (size_t)(kt * 64 + r) * D + nt * 64 + e4);
        T[r][e4] = f.x; T[r][e4 + 1] = f.y; T[r][e4 + 2] = f.z; T[r][e4 + 3] = f.w;
    }
    __syncthreads();
    ushort* dst = Wt + (size_t)i * D * D + (size_t)(nt * 64) * D + kt * 64;
#pragma unroll
    for (int it = 0; it < 4; ++it) {
        int idx = tid + it * 256;
        int e = idx >> 4, k4 = (idx & 15) * 4;
        ushort4 u;
        u.x = f2b(T[k4][e]); u.y = f2b(T[k4 + 1][e]);
        u.z = f2b(T[k4 + 2][e]); u.w = f2b(T[k4 + 3][e]);
        *(ushort4*)(dst + (size_t)e * D + k4) = u;
    }
}

// fc_W[k][n] (512,513) -> Wt[n][k] bf16, n padded to 576 with zeros
__global__ __launch_bounds__(256) void cvt_fc_k(const float* __restrict__ Wf,
                                                ushort* __restrict__ Wt)
{
    const int nt = blockIdx.x, kt = blockIdx.y;
    __shared__ float T[64][65];
    const int tid = threadIdx.x;
#pragma unroll
    for (int it = 0; it < 4; ++it) {
        int idx = tid + it * 256;
        int r = idx >> 4, e4 = (idx & 15) * 4;
#pragma unroll
        for (int j = 0; j < 4; ++j) {
            int n = nt * 64 + e4 + j;
            T[r][e4 + j] = (n < V) ? Wf[(size_t)(kt * 64 + r) * V + n] : 0.f;
        }
    }
    __syncthreads();
    ushort* dst = Wt + (size_t)(nt * 64) * 512 + kt * 64;
#pragma unroll
    for (int it = 0; it < 4; ++it) {
        int idx = tid + it * 256;
        int e = idx >> 4, k4 = (idx & 15) * 4;
        ushort4 u;
        u.x = f2b(T[k4][e]); u.y = f2b(T[k4 + 1][e]);
        u.z = f2b(T[k4 + 2][e]); u.w = f2b(T[k4 + 3][e]);
        *(ushort4*)(dst + (size_t)e * 512 + k4) = u;
    }
}

// ---------------------------------------------------------------------------
// bf16 MFMA GEMM: C[M x Ncols] = A[M x 512] * Bt[Ncols x 512]^T
// MODE 0: QKV (Ncols=1536): q/k bf16 (B,H,L,HS); v bf16 TRANSPOSED (B,H,HS,LP).
// MODE 1: MLP (Ncols=512):  o0 = gelu(acc+bias) + o0 (fp32, in-place h).
// MODE 2: FC  (Ncols=576p): o0[r*V+c] = acc + bias[c] (fp32), c < V.
// ---------------------------------------------------------------------------
template <int MODE>
__global__ __launch_bounds__(256) void mgemm_k(const ushort* __restrict__ A,
                                               const ushort* __restrict__ Bt,
                                               const float* __restrict__ bias,
                                               void* __restrict__ o0,
                                               void* __restrict__ o1,
                                               void* __restrict__ o2)
{
    __shared__ ushort As[64][72];
    __shared__ ushort Bs[64][72];
    const int tid  = threadIdx.x;
    const int wave = tid >> 6, lane = tid & 63;
    const int row0 = blockIdx.y * 64;
    const int col0 = blockIdx.x * 64;
    const int wr = (wave >> 1) * 32, wc = (wave & 1) * 32;
    const int frow = lane & 15;
    const int kb   = lane >> 4;

    f32x4 acc[2][2] = {};

    for (int k0 = 0; k0 < 512; k0 += 64) {
#pragma unroll
        for (int it = 0; it < 2; ++it) {
            int idx = tid + it * 256;
            int r = idx >> 3, kc = idx & 7;
            uint4 av = make_uint4(0u, 0u, 0u, 0u);
            if (row0 + r < BL)
                av = *(const uint4*)(A + (size_t)(row0 + r) * 512 + k0 + kc * 8);
            *(uint4*)&As[r][kc * 8] = av;
            uint4 bv = *(const uint4*)(Bt + (size_t)(col0 + r) * 512 + k0 + kc * 8);
            *(uint4*)&Bs[r][kc * 8] = bv;
        }
        __syncthreads();
#pragma unroll
        for (int ks = 0; ks < 2; ++ks) {
            bf16x8 a[2], b[2];
#pragma unroll
            for (int f = 0; f < 2; ++f) {
                a[f] = *(const bf16x8*)&As[wr + f * 16 + frow][ks * 32 + kb * 8];
                b[f] = *(const bf16x8*)&Bs[wc + f * 16 + frow][ks * 32 + kb * 8];
            }
#pragma unroll
            for (int fi = 0; fi < 2; ++fi)
#pragma unroll
                for (int fj = 0; fj < 2; ++fj)
                    acc[fi][fj] = __builtin_amdgcn_mfma_f32_16x16x32_bf16(
                        a[fi], b[fj], acc[fi][fj], 0, 0, 0);
        }
        __syncthreads();
    }

    // C frag layout: col = lane&15, row = (lane>>4)*4 + reg
    const int rbase = row0 + wr + (lane >> 4) * 4;
    const int cbase = col0 + wc + (lane & 15);
#pragma unroll
    for (int fi = 0; fi < 2; ++fi) {
#pragma unroll
        for (int fj = 0; fj < 2; ++fj) {
            const int c = cbase + fj * 16;
#pragma unroll
            for (int rg = 0; rg < 4; ++rg) {
                const int r = rbase + fi * 16 + rg;
                if (r >= BL) continue;
                float val = acc[fi][fj][rg];
                if (MODE == 0) {
                    int buf = c >> 9, cc = c & 511;
                    int b_ = r / L, l = r % L;
                    int head = cc >> 6, e = cc & 63;
                    int bh = b_ * H + head;
                    if (buf == 0)
                        ((ushort*)o0)[((size_t)bh * L + l) * HS + e] = f2b(val);
                    else if (buf == 1)
                        ((ushort*)o1)[((size_t)bh * L + l) * HS + e] = f2b(val);
                    else
                        ((ushort*)o2)[((size_t)bh * HS + e) * LP + l] = f2b(val);
                } else if (MODE == 1) {
                    float xv = val + bias[c];
                    float gl = 0.5f * xv * (1.f + erff(xv * 0.70710678118654752f));
                    ((float*)o0)[(size_t)r * D + c] = gl + ((float*)o0)[(size_t)r * D + c];
                } else {
                    if (c < V) ((float*)o0)[(size_t)r * V + c] = val + bias[c];
                }
            }
        }
    }
}

// ---------------------------------------------------------------------------
// MFMA flash attention: one block per (b,h,q-tile of 64). 4 waves, each owns
// 16 q-rows. Q/K tiles [row][e] bf16; Vt tile [e][kv] bf16 (from transposed
// global); P tile [q][m] bf16 written by owning wave, read back as A-frags
// (wave-local, no extra barrier). Softmax fp32 in registers; MFMA C-layout
// (row=(lane>>4)*4+rg) matches across S and O so m/l/rescale are in-lane.
// ---------------------------------------------------------------------------
__global__ __launch_bounds__(256) void fattn_k(const ushort* __restrict__ qb,
                                               const ushort* __restrict__ kb,
                                               const ushort* __restrict__ vT,
                                               float* __restrict__ hbuf)
{
    __shared__ ushort Qs[64][72];
    __shared__ ushort Ks[64][72];
    __shared__ ushort Vs[64][72];   // [e][kv]
    __shared__ ushort Ps[64][72];

    const int bx  = blockIdx.x;
    const int bh  = bx / 9;
    const int qt  = 8 - (bx % 9);        // big tiles dispatched first
    const int q0  = qt * 64;
    const int tid = threadIdx.x;
    const int wave = tid >> 6, lane = tid & 63;
    const int lg = lane >> 4, li = lane & 15;
    const int wq = wave * 16;

    // ---- stage Q (bf16, [q][e]) ----
#pragma unroll
    for (int it = 0; it < 2; ++it) {
        int idx = tid + it * 256;
        int r = idx >> 3, c8 = (idx & 7) * 8;
        int qr = q0 + r;
        uint4 val = make_uint4(0u, 0u, 0u, 0u);
        if (qr < L) val = *(const uint4*)(qb + ((size_t)bh * L + qr) * HS + c8);
        *(uint4*)&Qs[r][c8] = val;
    }

    float m_run[4], l_run[4];
    f32x4 accO[4] = {};
#pragma unroll
    for (int rg = 0; rg < 4; ++rg) { m_run[rg] = -INFINITY; l_run[rg] = 0.f; }

    const int n_mt = qt + 1;

    for (int t = 0; t < n_mt; ++t) {
        const int m0 = t * 64;
        // ---- stage K [m][e] and Vt [e][kv] ----
#pragma unroll
        for (int it = 0; it < 2; ++it) {
            int idx = tid + it * 256;
            int r = idx >> 3, c8 = (idx & 7) * 8;
            int mr = m0 + r;
            uint4 kv = make_uint4(0u, 0u, 0u, 0u);
            if (mr < L) kv = *(const uint4*)(kb + ((size_t)bh * L + mr) * HS + c8);
            *(uint4*)&Ks[r][c8] = kv;
            int mc = m0 + c8;
            uint4 vv = make_uint4(0u, 0u, 0u, 0u);
            if (mc + 7 < L) {
                vv = *(const uint4*)(vT + ((size_t)bh * HS + r) * LP + mc);
            } else {
                ushort tmp[8] = {0, 0, 0, 0, 0, 0, 0, 0};
#pragma unroll
                for (int j2 = 0; j2 < 8; ++j2)
                    if (mc + j2 < L) tmp[j2] = vT[((size_t)bh * HS + r) * LP + mc + j2];
                vv = *(uint4*)tmp;
            }
            *(uint4*)&Vs[r][c8] = vv;
        }
        __syncthreads();

        // ---- S = Q K^T (wave rows wq..wq+15, all 64 cols) ----
        f32x4 accS[4] = {};
#pragma unroll
        for (int ks = 0; ks < 2; ++ks) {
            bf16x8 a = *(const bf16x8*)&Qs[wq + li][ks * 32 + lg * 8];
#pragma unroll
            for (int j = 0; j < 4; ++j) {
                bf16x8 b = *(const bf16x8*)&Ks[j * 16 + li][ks * 32 + lg * 8];
                accS[j] = __builtin_amdgcn_mfma_f32_16x16x32_bf16(a, b, accS[j], 0, 0, 0);
            }
        }

        // ---- mask + online softmax (row = wq + lg*4 + rg, col = j*16 + li) ----
#pragma unroll
        for (int rg = 0; rg < 4; ++rg) {
            const int qrow = q0 + wq + lg * 4 + rg;
            float sv[4];
            float rmax = -INFINITY;
#pragma unroll
            for (int j = 0; j < 4; ++j) {
                int mcol = m0 + j * 16 + li;
                float s = accS[j][rg] * 0.125f;
                if (mcol > qrow || mcol >= L) s = -INFINITY;
                sv[j] = s;
                rmax = fmaxf(rmax, s);
            }
            rmax = fmaxf(rmax, __shfl_xor(rmax, 1));
            rmax = fmaxf(rmax, __shfl_xor(rmax, 2));
            rmax = fmaxf(rmax, __shfl_xor(rmax, 4));
            rmax = fmaxf(rmax, __shfl_xor(rmax, 8));
            const float mnew = fmaxf(m_run[rg], rmax);
            const float fs = __expf(m_run[rg] - mnew);
            float psum = 0.f;
#pragma unroll
            for (int j = 0; j < 4; ++j) {
                float p = __expf(sv[j] - mnew);
                psum += p;
                Ps[wq + lg * 4 + rg][j * 16 + li] = f2b(p);
            }
            psum += __shfl_xor(psum, 1);
            psum += __shfl_xor(psum, 2);
            psum += __shfl_xor(psum, 4);
            psum += __shfl_xor(psum, 8);
            l_run[rg] = l_run[rg] * fs + psum;
            m_run[rg] = mnew;
#pragma unroll
            for (int j = 0; j < 4; ++j) accO[j][rg] *= fs;
        }

        // ---- O += P V (A-frags from own wave's P rows; B from Vt) ----
#pragma unroll
        for (int ks = 0; ks < 2; ++ks) {
            bf16x8 a = *(const bf16x8*)&Ps[wq + li][ks * 32 + lg * 8];
#pragma unroll
            for (int j = 0; j < 4; ++j) {
                bf16x8 b = *(const bf16x8*)&Vs[j * 16 + li][ks * 32 + lg * 8];
                accO[j] = __builtin_amdgcn_mfma_f32_16x16x32_bf16(a, b, accO[j], 0, 0, 0);
            }
        }
        __syncthreads();   // protect Ks/Vs before next tile's staging
    }

    // ---- epilogue: h += O / l ----
    const int b_ = bh / H, hh = bh % H;
#pragma unroll
    for (int rg = 0; rg < 4; ++rg) {
        const int qrow = q0 + wq + lg * 4 + rg;
        if (qrow >= L) continue;
        const float inv = 1.f / l_run[rg];
        float* dst = hbuf + ((size_t)b_ * L + qrow) * D + hh * HS;
#pragma unroll
        for (int j = 0; j < 4; ++j)
            dst[j * 16 + li] += accO[j][rg] * inv;
    }
}

// ---------------------------------------------------------------------------
extern "C" void kernel_launch(void* const* d_in, const int* in_sizes, int n_in,
                              void* d_out, int out_size, void* d_ws, size_t ws_size,
                              hipStream_t stream)
{
    const int*   x    = (const int*)d_in[0];
    const float* emb  = (const float*)d_in[1];
    const float* pos  = (const float*)d_in[2];
    const float* Wq   = (const float*)d_in[3];
    const float* Wk   = (const float*)d_in[4];
    const float* Wv   = (const float*)d_in[5];
    const float* ln1g = (const float*)d_in[6];
    const float* ln1b = (const float*)d_in[7];
    const float* ln2g = (const float*)d_in[8];
    const float* ln2b = (const float*)d_in[9];
    const float* mlpW = (const float*)d_in[10];
    const float* mlpb = (const float*)d_in[11];
    const float* fcW  = (const float*)d_in[12];
    const float* fcb  = (const float*)d_in[13];
    float* out = (float*)d_out;

    // workspace layout — all 16B aligned
    char* ws = (char*)d_ws;
    float*  h   = (float*)ws;    ws += (size_t)BL * D * 4;
    ushort* qb  = (ushort*)ws;   ws += (size_t)BL * D * 2;
    ushort* kb  = (ushort*)ws;   ws += (size_t)BL * D * 2;
    ushort* vT  = (ushort*)ws;   ws += (size_t)B * H * HS * LP * 2;
    ushort* xnb = (ushort*)ws;   ws += (size_t)BL * D * 2;
    ushort* hb  = (ushort*)ws;   ws += (size_t)BL * D * 2;
    ushort* Wp  = (ushort*)ws;   ws += (size_t)NL * 1536 * 512 * 2;
    ushort* Wtm = (ushort*)ws;   ws += (size_t)NL * D * D * 2;
    ushort* Wtf = (ushort*)ws;   ws += (size_t)576 * 512 * 2;

    cvt_qkv_k<<<dim3(8, NL * H, 3), 256, 0, stream>>>(Wq, Wk, Wv, Wp);
    cvt_mlp_k<<<dim3(8, 8, NL), 256, 0, stream>>>(mlpW, Wtm);
    cvt_fc_k<<<dim3(9, 8), 256, 0, stream>>>(fcW, Wtf);

    embed_k<<<BL, 256, 0, stream>>>(x, emb, pos, h);

    for (int i = 0; i < NL; ++i) {
        ln_k<<<BL, 256, 0, stream>>>(h, ln1g + i * D, ln1b + i * D, xnb);
        mgemm_k<0><<<dim3(24, 65), 256, 0, stream>>>(
            xnb, Wp + (size_t)i * 1536 * 512, nullptr, qb, kb, vT);
        fattn_k<<<B * H * 9, 256, 0, stream>>>(qb, kb, vT, h);
        ln_k<<<BL, 256, 0, stream>>>(h, ln2g + i * D, ln2b + i * D, xnb);
        mgemm_k<1><<<dim3(8, 65), 256, 0, stream>>>(
            xnb, Wtm + (size_t)i * D * D, mlpb + i * D, h, nullptr, nullptr);
    }
    h2bf_k<<<BL * D / 1024, 256, 0, stream>>>(h, hb);
    mgemm_k<2><<<dim3(9, 65), 256, 0, stream>>>(hb, Wtf, fcb, out, nullptr, nullptr);
}